// Round 2
// baseline (252.641 us; speedup 1.0000x reference)
//
#include <hip/hip_runtime.h>

#define BB 2
#define LL 2048
#define EE 1024
#define HH 16
#define HDD 64

typedef __bf16 bf16x8 __attribute__((ext_vector_type(8)));
typedef float f32x4 __attribute__((ext_vector_type(4)));

__device__ __forceinline__ unsigned short f2bf(float f) {
  unsigned int x = __float_as_uint(f);
  return (unsigned short)((x + 0x7FFFu + ((x >> 16) & 1u)) >> 16);  // RNE
}

__device__ __forceinline__ void load_lds16(const void* g, void* l) {
  __builtin_amdgcn_global_load_lds(
      (const __attribute__((address_space(1))) void*)g,
      (__attribute__((address_space(3))) void*)l, 16, 0, 0);
}

// ---------------- prelude: cast fp32->bf16 (blocks 0..10239) +
//                  column sums of key/value (blocks 10240..10751) -------------
__global__ __launch_bounds__(256) void prelude_kernel(
    const float* __restrict__ q, const float* __restrict__ pe,
    const float* __restrict__ wq, const float* __restrict__ wp,
    unsigned short* __restrict__ q16, unsigned short* __restrict__ pe16,
    unsigned short* __restrict__ wq16, unsigned short* __restrict__ wp16,
    const float* __restrict__ key, const float* __restrict__ value,
    float* __restrict__ keysum, float* __restrict__ valsum) {
  if (blockIdx.x < 10240) {
    const int NQ4 = BB * LL * EE / 4;   // 1048576 float4s
    const int NW4 = EE * EE / 4;        // 262144
    int i = blockIdx.x * 256 + threadIdx.x;
    const float* src; unsigned short* dst; int off;
    if (i < NQ4)                { src = q;  dst = q16;  off = i; }
    else if (i < 2 * NQ4)       { src = pe; dst = pe16; off = i - NQ4; }
    else if (i < 2 * NQ4 + NW4) { src = wq; dst = wq16; off = i - 2 * NQ4; }
    else                        { src = wp; dst = wp16; off = i - 2 * NQ4 - NW4; }
    float4 v = ((const float4*)src)[off];
    ushort4 u;
    u.x = f2bf(v.x); u.y = f2bf(v.y); u.z = f2bf(v.z); u.w = f2bf(v.w);
    ((ushort4*)dst)[off] = u;
  } else {
    int blk2 = blockIdx.x - 10240;       // [0, 512)
    int b = blk2 >> 8;
    int ch = (blk2 >> 2) & 63;
    int es = blk2 & 3;
    int e = es * 256 + threadIdx.x;
    size_t base = ((size_t)b * LL + ch * 32) * EE + e;
    float ak = 0.f, av = 0.f;
    for (int i = 0; i < 32; i++) {
      ak += key[base + (size_t)i * EE];
      av += value[base + (size_t)i * EE];
    }
    atomicAdd(&keysum[b * EE + e], ak);
    atomicAdd(&valsum[b * EE + e], av);
  }
}

// ---------------- project summed key/value: sum @ W.T + L*bias ---------------
__global__ __launch_bounds__(256) void proj_kernel(
    const float* __restrict__ keysum, const float* __restrict__ valsum,
    const float* __restrict__ Wk, const float* __restrict__ bk,
    const float* __restrict__ Wv, const float* __restrict__ bv,
    float* __restrict__ Kproj, float* __restrict__ Vproj) {
  int wv = threadIdx.x >> 6, lane = threadIdx.x & 63;
  int idx = blockIdx.x * 4 + wv;          // [0, BB*EE)
  int b = idx >> 10, ep = idx & (EE - 1);
  const float* sum  = blockIdx.z ? valsum : keysum;
  const float* W    = blockIdx.z ? Wv : Wk;
  const float* bias = blockIdx.z ? bv : bk;
  float* outp       = blockIdx.z ? Vproj : Kproj;
  float acc = 0.f;
  for (int k = lane; k < EE; k += 64) acc += sum[b * EE + k] * W[ep * EE + k];
  for (int off = 32; off; off >>= 1) acc += __shfl_down(acc, off, 64);
  if (lane == 0) outp[b * EE + ep] = acc + (float)LL * bias[ep];
}

// ---------------- W2[b,h,e] = sum_d Vproj[b,h*64+d] * Wo[e, h*64+d] ----------
__global__ __launch_bounds__(256) void w2_kernel(
    const float* __restrict__ Vproj, const float* __restrict__ Wo,
    float* __restrict__ W2) {
  int wv = threadIdx.x >> 6, lane = threadIdx.x & 63;
  int idx = blockIdx.x * 4 + wv;          // [0, 32768)
  int e = idx & (EE - 1);
  int h = (idx >> 10) & (HH - 1);
  int b = idx >> 14;
  float acc = Vproj[b * EE + h * HDD + lane] * Wo[(size_t)e * EE + h * HDD + lane];
  for (int off = 32; off; off >>= 1) acc += __shfl_down(acc, off, 64);
  if (lane == 0) W2[((size_t)b * HH + h) * EE + e] = acc;
}

// ---------------- bf16 MFMA GEMM: Out[M,N] = X[M,K] @ W[N,K]^T (+bias) -------
// 128x128 tile, BK=32, global_load_lds width=16 staging (m97 structure).
// grid (8, 32, 2): z=0 -> q projection (+bq), z=1 -> r projection.
__global__ __launch_bounds__(256) void gemm_kernel(
    const unsigned short* __restrict__ q16, const unsigned short* __restrict__ wq16,
    const float* __restrict__ bq, float* __restrict__ qout,
    const unsigned short* __restrict__ pe16, const unsigned short* __restrict__ wp16,
    float* __restrict__ rout) {
  const int K = EE, N = EE;
  const unsigned short* X; const unsigned short* W; const float* bias; float* Out;
  if (blockIdx.z == 0) { X = q16;  W = wq16; bias = bq;      Out = qout; }
  else                 { X = pe16; W = wp16; bias = nullptr; Out = rout; }

  __shared__ __align__(16) unsigned short As[128 * 32];  // 8 KB
  __shared__ __align__(16) unsigned short Bs[128 * 32];

  const int tid = threadIdx.x;
  const int lane = tid & 63;
  const int wv = tid >> 6;
  const int wr = wv >> 1, wc = wv & 1;
  const int n0 = blockIdx.x * 128;
  const int m0 = blockIdx.y * 128;

  // staging mapping: lane l of wave wv -> LDS ushort idx wv*512 + l*8
  //   row = wv*16 + l/4, col = (l%4)*8  (row-major [128 x 32], no padding)
  const int srow = wv * 16 + (lane >> 2);
  const int scol = (lane & 3) * 8;
  const unsigned short* gA = X + (size_t)(m0 + srow) * K + scol;
  const unsigned short* gB = W + (size_t)(n0 + srow) * K + scol;
  unsigned short* sA = As + wv * 512;   // wave-uniform base
  unsigned short* sB = Bs + wv * 512;

  f32x4 acc[4][4];
#pragma unroll
  for (int i = 0; i < 4; i++)
#pragma unroll
    for (int j = 0; j < 4; j++) acc[i][j] = (f32x4)0.0f;

  const int arow = wr * 64 + (lane & 15);
  const int brow = wc * 64 + (lane & 15);
  const int koff = (lane >> 4) * 8;

  for (int kk = 0; kk < K; kk += 32) {
    load_lds16(gA + kk,                   sA);
    load_lds16(gA + kk + (size_t)64 * K,  sA + 2048);
    load_lds16(gB + kk,                   sB);
    load_lds16(gB + kk + (size_t)64 * K,  sB + 2048);
    __syncthreads();
    bf16x8 af[4], bf[4];
#pragma unroll
    for (int i = 0; i < 4; i++) af[i] = *(const bf16x8*)&As[(arow + i * 16) * 32 + koff];
#pragma unroll
    for (int j = 0; j < 4; j++) bf[j] = *(const bf16x8*)&Bs[(brow + j * 16) * 32 + koff];
#pragma unroll
    for (int i = 0; i < 4; i++)
#pragma unroll
      for (int j = 0; j < 4; j++)
        acc[i][j] = __builtin_amdgcn_mfma_f32_16x16x32_bf16(af[i], bf[j], acc[i][j], 0, 0, 0);
    __syncthreads();
  }

  // epilogue: C/D layout col=lane&15, row=(lane>>4)*4+g  [verified m89/m91]
  const int rbase = m0 + wr * 64 + (lane >> 4) * 4;
  const int cbase = n0 + wc * 64 + (lane & 15);
#pragma unroll
  for (int i = 0; i < 4; i++) {
#pragma unroll
    for (int j = 0; j < 4; j++) {
      int col = cbase + j * 16;
      float badd = bias ? bias[col] : 0.f;
#pragma unroll
      for (int g = 0; g < 4; g++) {
        int row = rbase + i * 16 + g;
        Out[(size_t)row * N + col] = acc[i][j][g] + badd;
      }
    }
  }
}

// ---------------- prefix scan of r: stage 1 (64 chunk sums of 32 rows) -------
// grid (4, 64, BB)
__global__ __launch_bounds__(256) void scan1_kernel(
    const float* __restrict__ r, float* __restrict__ chunksum) {
  int e = blockIdx.x * 256 + threadIdx.x;
  int ch = blockIdx.y, b = blockIdx.z;
  size_t base = ((size_t)b * LL + ch * 32) * EE + e;
  float a = 0.f;
  for (int i = 0; i < 32; i++) a += r[base + (size_t)i * EE];
  chunksum[((size_t)b * 64 + ch) * EE + e] = a;
}

// ---------------- prefix scan stage 2: write P[b, m, e], m = 0..L ------------
// grid (4, 64, BB)
__global__ __launch_bounds__(256) void scan2_kernel(
    const float* __restrict__ r, const float* __restrict__ chunksum,
    float* __restrict__ P) {
  int e = blockIdx.x * 256 + threadIdx.x;
  int ch = blockIdx.y, b = blockIdx.z;
  float pre = 0.f;
  for (int c = 0; c < ch; c++) pre += chunksum[((size_t)b * 64 + c) * EE + e];
  size_t Pbase = (size_t)b * (LL + 1) * EE;
  if (ch == 0) P[Pbase + e] = 0.f;
  size_t rbase = ((size_t)b * LL + ch * 32) * EE + e;
  float run = pre;
  for (int i = 0; i < 32; i++) {
    run += r[rbase + (size_t)i * EE];
    P[Pbase + (size_t)(ch * 32 + i + 1) * EE + e] = run;
  }
}

// ---------------- score row-sums S[b,h,p] ------------------------------------
// one wave per (b,p); float4 loads, 16-lane group reduction (4 heads/iter).
// S*32 = (q+U).Kproj + (q+V).(P[L]-P[L-p-1]) + (q_{p+1}+V).P[L-p-2]
__global__ __launch_bounds__(256) void score_kernel(
    const float* __restrict__ q, const float* __restrict__ P,
    const float* __restrict__ Kproj, const float* __restrict__ U,
    const float* __restrict__ V, float* __restrict__ S) {
  int wv = threadIdx.x >> 6, lane = threadIdx.x & 63;
  int g = blockIdx.x * 4 + wv;            // [0, BB*LL)
  int b = g >> 11, p = g & (LL - 1);
  size_t qrow = (size_t)(b * LL + p) * EE;
  size_t Pbase = (size_t)b * (LL + 1) * EE;
  bool hasB = (p < LL - 1);
  const float4* qv  = (const float4*)(q + qrow);
  const float4* q2v = (const float4*)(q + qrow + EE);
  const float4* PLv = (const float4*)(P + Pbase + (size_t)LL * EE);
  const float4* PAv = (const float4*)(P + Pbase + (size_t)(LL - p - 1) * EE);
  const float4* PBv = (const float4*)(P + Pbase + (size_t)(hasB ? (LL - p - 2) : 0) * EE);
  const float4* KPv = (const float4*)(Kproj + b * EE);
  const float4* Uv  = (const float4*)U;
  const float4* Vv  = (const float4*)V;
#pragma unroll
  for (int it = 0; it < 4; it++) {
    int idx = it * 64 + lane;             // float4 index; d0 = idx*4
    float4 qd = qv[idx];
    float4 kp = KPv[idx], pl = PLv[idx], pa = PAv[idx];
    float4 Uh = Uv[idx], Vh = Vv[idx];
    float4 q2 = hasB ? q2v[idx] : make_float4(0.f, 0.f, 0.f, 0.f);
    float4 pb = hasB ? PBv[idx] : make_float4(0.f, 0.f, 0.f, 0.f);
    float t = (qd.x + Uh.x) * kp.x + (qd.x + Vh.x) * (pl.x - pa.x) + (q2.x + Vh.x) * pb.x
            + (qd.y + Uh.y) * kp.y + (qd.y + Vh.y) * (pl.y - pa.y) + (q2.y + Vh.y) * pb.y
            + (qd.z + Uh.z) * kp.z + (qd.z + Vh.z) * (pl.z - pa.z) + (q2.z + Vh.z) * pb.z
            + (qd.w + Uh.w) * kp.w + (qd.w + Vh.w) * (pl.w - pa.w) + (q2.w + Vh.w) * pb.w;
    t += __shfl_down(t, 8, 64);
    t += __shfl_down(t, 4, 64);
    t += __shfl_down(t, 2, 64);
    t += __shfl_down(t, 1, 64);
    if ((lane & 15) == 0) {
      int h = it * 4 + (lane >> 4);
      S[((size_t)b * HH + h) * LL + p] = t * (1.f / 32.f);
    }
  }
}

// ---------------- output: out[b,p,:] = sum_h S[b,h,p]*W2[b,h,:] + bo ---------
// grid BB*LL blocks, block 256; one float4 per thread
__global__ __launch_bounds__(256) void out_kernel(
    const float* __restrict__ S, const float* __restrict__ W2,
    const float* __restrict__ bo, float* __restrict__ out) {
  int row = blockIdx.x;                   // [0, BB*LL)
  int b = row >> 11, p = row & (LL - 1);
  __shared__ float sh[HH];
  if (threadIdx.x < HH) sh[threadIdx.x] = S[((size_t)b * HH + threadIdx.x) * LL + p];
  __syncthreads();
  int e4 = threadIdx.x;                   // 256 float4 = 1024 floats
  const float4* W2v = (const float4*)W2;
  float4 acc = ((const float4*)bo)[e4];
#pragma unroll
  for (int h = 0; h < HH; h++) {
    float s = sh[h];
    float4 w = W2v[((size_t)b * HH + h) * 256 + e4];
    acc.x += s * w.x; acc.y += s * w.y; acc.z += s * w.z; acc.w += s * w.w;
  }
  ((float4*)out)[(size_t)row * 256 + e4] = acc;
}

extern "C" void kernel_launch(void* const* d_in, const int* in_sizes, int n_in,
                              void* d_out, int out_size, void* d_ws, size_t ws_size,
                              hipStream_t stream) {
  const float* query = (const float*)d_in[0];
  const float* key   = (const float*)d_in[1];
  const float* value = (const float*)d_in[2];
  const float* pos   = (const float*)d_in[3];
  const float* Wq = (const float*)d_in[4];
  const float* bq = (const float*)d_in[5];
  const float* Wk = (const float*)d_in[6];
  const float* bk = (const float*)d_in[7];
  const float* Wv = (const float*)d_in[8];
  const float* bv = (const float*)d_in[9];
  const float* Wp = (const float*)d_in[10];
  const float* Wo = (const float*)d_in[11];
  const float* bo = (const float*)d_in[12];
  const float* U  = (const float*)d_in[13];
  const float* V  = (const float*)d_in[14];
  float* out = (float*)d_out;

  char* ws = (char*)d_ws;
  size_t o = 0;
  auto take = [&](size_t bytes) -> char* {
    char* p = ws + o;
    o += (bytes + 255) & ~(size_t)255;
    return p;
  };
  float* keysum = (float*)take(BB * EE * 4);
  float* valsum = (float*)take(BB * EE * 4);
  float* Kproj  = (float*)take(BB * EE * 4);
  float* Vproj  = (float*)take(BB * EE * 4);
  float* W2     = (float*)take((size_t)BB * HH * EE * 4);
  float* S      = (float*)take((size_t)BB * HH * LL * 4);
  float* chunks = (float*)take((size_t)BB * 64 * EE * 4);
  float* qbuf   = (float*)take((size_t)BB * LL * EE * 4);
  float* rbuf   = (float*)take((size_t)BB * LL * EE * 4);
  float* Pbuf   = (float*)take((size_t)BB * (LL + 1) * EE * 4);
  unsigned short* q16  = (unsigned short*)take((size_t)BB * LL * EE * 2);
  unsigned short* pe16 = (unsigned short*)take((size_t)BB * LL * EE * 2);
  unsigned short* wq16 = (unsigned short*)take((size_t)EE * EE * 2);
  unsigned short* wp16 = (unsigned short*)take((size_t)EE * EE * 2);

  // zero the atomic accumulators (keysum, valsum are adjacent)
  hipMemsetAsync(keysum, 0, (size_t)2 * BB * EE * 4, stream);

  prelude_kernel<<<10752, 256, 0, stream>>>(query, pos, Wq, Wp, q16, pe16, wq16, wp16,
                                            key, value, keysum, valsum);
  proj_kernel<<<dim3(BB * EE / 4, 1, 2), 256, 0, stream>>>(keysum, valsum, Wk, bk, Wv, bv, Kproj, Vproj);
  w2_kernel<<<dim3(BB * HH * EE / 4), 256, 0, stream>>>(Vproj, Wo, W2);
  gemm_kernel<<<dim3(EE / 128, BB * LL / 128, 2), 256, 0, stream>>>(q16, wq16, bq, qbuf, pe16, wp16, rbuf);
  scan1_kernel<<<dim3(EE / 256, 64, BB), 256, 0, stream>>>(rbuf, chunks);
  scan2_kernel<<<dim3(EE / 256, 64, BB), 256, 0, stream>>>(rbuf, chunks, Pbuf);
  score_kernel<<<dim3(BB * LL / 4), 256, 0, stream>>>(qbuf, Pbuf, Kproj, U, V, S);
  out_kernel<<<dim3(BB * LL), 256, 0, stream>>>(S, W2, bo, out);
}

// Round 3
// 230.046 us; speedup vs baseline: 1.0982x; 1.0982x over previous
//
#include <hip/hip_runtime.h>

#define BB 2
#define LL 2048
#define EE 1024
#define HH 16
#define HDD 64

typedef __bf16 bf16x8 __attribute__((ext_vector_type(8)));
typedef float f32x4 __attribute__((ext_vector_type(4)));

__device__ __forceinline__ unsigned short f2bf(float f) {
  unsigned int x = __float_as_uint(f);
  return (unsigned short)((x + 0x7FFFu + ((x >> 16) & 1u)) >> 16);  // RNE
}

__device__ __forceinline__ void load_lds16(const void* g, void* l) {
  __builtin_amdgcn_global_load_lds(
      (const __attribute__((address_space(1))) void*)g,
      (__attribute__((address_space(3))) void*)l, 16, 0, 0);
}

// ---------------- prelude: grid-stride cast (blocks 0..1279) +
//                  column sums of key/value (blocks 1280..1407) --------------
#define CAST_BLOCKS 1280
#define CAST_STRIDE (CAST_BLOCKS * 256)   // 327680 float4s per sweep
__global__ __launch_bounds__(256) void prelude_kernel(
    const float* __restrict__ q, const float* __restrict__ pe,
    const float* __restrict__ wq, const float* __restrict__ wp,
    unsigned short* __restrict__ q16, unsigned short* __restrict__ pe16,
    unsigned short* __restrict__ wq16, unsigned short* __restrict__ wp16,
    const float* __restrict__ key, const float* __restrict__ value,
    float* __restrict__ keysum, float* __restrict__ valsum) {
  if (blockIdx.x < CAST_BLOCKS) {
    const int NQ4 = BB * LL * EE / 4;   // 1048576 float4s each for q, pe
    const int NW4 = EE * EE / 4;        // 262144 each for wq, wp
    int t = blockIdx.x * 256 + threadIdx.x;
    float4 v[8]; unsigned short* dst[8]; int off[8];
#pragma unroll
    for (int k = 0; k < 8; k++) {
      int i = t + k * CAST_STRIDE;      // total = 8*327680 = 2621440 exactly
      const float* src;
      if (i < NQ4)                { src = q;  dst[k] = q16;  off[k] = i; }
      else if (i < 2 * NQ4)       { src = pe; dst[k] = pe16; off[k] = i - NQ4; }
      else if (i < 2 * NQ4 + NW4) { src = wq; dst[k] = wq16; off[k] = i - 2 * NQ4; }
      else                        { src = wp; dst[k] = wp16; off[k] = i - 2 * NQ4 - NW4; }
      v[k] = ((const float4*)src)[off[k]];
    }
#pragma unroll
    for (int k = 0; k < 8; k++) {
      ushort4 u;
      u.x = f2bf(v[k].x); u.y = f2bf(v[k].y); u.z = f2bf(v[k].z); u.w = f2bf(v[k].w);
      ((ushort4*)dst[k])[off[k]] = u;
    }
  } else {
    int blk2 = blockIdx.x - CAST_BLOCKS;  // [0, 128): 2 b x 64 chunks of 32 rows
    int b = blk2 >> 6, ch = blk2 & 63;
    int tid = threadIdx.x;                // float4 index within E (256*4 = 1024)
    const float4* k4 = (const float4*)(key   + ((size_t)b * LL + ch * 32) * EE);
    const float4* v4 = (const float4*)(value + ((size_t)b * LL + ch * 32) * EE);
    float4 ak = make_float4(0.f, 0.f, 0.f, 0.f);
    float4 av = make_float4(0.f, 0.f, 0.f, 0.f);
#pragma unroll 4
    for (int i = 0; i < 32; i++) {
      float4 kk = k4[i * 256 + tid];
      float4 vv = v4[i * 256 + tid];
      ak.x += kk.x; ak.y += kk.y; ak.z += kk.z; ak.w += kk.w;
      av.x += vv.x; av.y += vv.y; av.z += vv.z; av.w += vv.w;
    }
    int e = tid * 4;
    atomicAdd(&keysum[b * EE + e + 0], ak.x);
    atomicAdd(&keysum[b * EE + e + 1], ak.y);
    atomicAdd(&keysum[b * EE + e + 2], ak.z);
    atomicAdd(&keysum[b * EE + e + 3], ak.w);
    atomicAdd(&valsum[b * EE + e + 0], av.x);
    atomicAdd(&valsum[b * EE + e + 1], av.y);
    atomicAdd(&valsum[b * EE + e + 2], av.z);
    atomicAdd(&valsum[b * EE + e + 3], av.w);
  }
}

// ---------------- project summed key/value: sum @ W.T + L*bias ---------------
__global__ __launch_bounds__(256) void proj_kernel(
    const float* __restrict__ keysum, const float* __restrict__ valsum,
    const float* __restrict__ Wk, const float* __restrict__ bk,
    const float* __restrict__ Wv, const float* __restrict__ bv,
    float* __restrict__ Kproj, float* __restrict__ Vproj) {
  int wv = threadIdx.x >> 6, lane = threadIdx.x & 63;
  int idx = blockIdx.x * 4 + wv;          // [0, BB*EE)
  int b = idx >> 10, ep = idx & (EE - 1);
  const float* sum  = blockIdx.z ? valsum : keysum;
  const float* W    = blockIdx.z ? Wv : Wk;
  const float* bias = blockIdx.z ? bv : bk;
  float* outp       = blockIdx.z ? Vproj : Kproj;
  float acc = 0.f;
  for (int k = lane; k < EE; k += 64) acc += sum[b * EE + k] * W[ep * EE + k];
  for (int off = 32; off; off >>= 1) acc += __shfl_down(acc, off, 64);
  if (lane == 0) outp[b * EE + ep] = acc + (float)LL * bias[ep];
}

// ---------------- W2[b,h,e] = sum_d Vproj[b,h*64+d] * Wo[e, h*64+d] ----------
__global__ __launch_bounds__(256) void w2_kernel(
    const float* __restrict__ Vproj, const float* __restrict__ Wo,
    float* __restrict__ W2) {
  int wv = threadIdx.x >> 6, lane = threadIdx.x & 63;
  int idx = blockIdx.x * 4 + wv;          // [0, 32768)
  int e = idx & (EE - 1);
  int h = (idx >> 10) & (HH - 1);
  int b = idx >> 14;
  float acc = Vproj[b * EE + h * HDD + lane] * Wo[(size_t)e * EE + h * HDD + lane];
  for (int off = 32; off; off >>= 1) acc += __shfl_down(acc, off, 64);
  if (lane == 0) W2[((size_t)b * HH + h) * EE + e] = acc;
}

// ---------------- bf16 MFMA GEMM: Out[M,N] = X[M,K] @ W[N,K]^T (+bias) -------
// 128x128 tile, BK=32, global_load_lds width=16 staging (m97 structure).
// z=0 -> q projection (+bq); z=1 -> r projection + fused chunk row-sums.
__global__ __launch_bounds__(256) void gemm_kernel(
    const unsigned short* __restrict__ q16, const unsigned short* __restrict__ wq16,
    const float* __restrict__ bq, float* __restrict__ qout,
    const unsigned short* __restrict__ pe16, const unsigned short* __restrict__ wp16,
    float* __restrict__ rout, float* __restrict__ chunks) {
  const int K = EE, N = EE;
  const unsigned short* X; const unsigned short* W; const float* bias; float* Out;
  if (blockIdx.z == 0) { X = q16;  W = wq16; bias = bq;      Out = qout; }
  else                 { X = pe16; W = wp16; bias = nullptr; Out = rout; }

  __shared__ __align__(16) unsigned short As[128 * 32];  // 8 KB
  __shared__ __align__(16) unsigned short Bs[128 * 32];

  const int tid = threadIdx.x;
  const int lane = tid & 63;
  const int wv = tid >> 6;
  const int wr = wv >> 1, wc = wv & 1;
  const int n0 = blockIdx.x * 128;
  const int m0 = blockIdx.y * 128;

  // staging: lane l of wave wv -> LDS ushort idx wv*512 + l*8 == row-major
  //   row = wv*16 + l/4, col = (l%4)*8 of a [128 x 32] tile (no padding)
  const int srow = wv * 16 + (lane >> 2);
  const int scol = (lane & 3) * 8;
  const unsigned short* gA = X + (size_t)(m0 + srow) * K + scol;
  const unsigned short* gB = W + (size_t)(n0 + srow) * K + scol;
  unsigned short* sA = As + wv * 512;   // wave-uniform base
  unsigned short* sB = Bs + wv * 512;

  f32x4 acc[4][4];
#pragma unroll
  for (int i = 0; i < 4; i++)
#pragma unroll
    for (int j = 0; j < 4; j++) acc[i][j] = (f32x4)0.0f;

  const int arow = wr * 64 + (lane & 15);
  const int brow = wc * 64 + (lane & 15);
  const int koff = (lane >> 4) * 8;

  for (int kk = 0; kk < K; kk += 32) {
    load_lds16(gA + kk,                   sA);
    load_lds16(gA + kk + (size_t)64 * K,  sA + 2048);
    load_lds16(gB + kk,                   sB);
    load_lds16(gB + kk + (size_t)64 * K,  sB + 2048);
    __syncthreads();
    bf16x8 af[4], bf[4];
#pragma unroll
    for (int i = 0; i < 4; i++) af[i] = *(const bf16x8*)&As[(arow + i * 16) * 32 + koff];
#pragma unroll
    for (int j = 0; j < 4; j++) bf[j] = *(const bf16x8*)&Bs[(brow + j * 16) * 32 + koff];
#pragma unroll
    for (int i = 0; i < 4; i++)
#pragma unroll
      for (int j = 0; j < 4; j++)
        acc[i][j] = __builtin_amdgcn_mfma_f32_16x16x32_bf16(af[i], bf[j], acc[i][j], 0, 0, 0);
    __syncthreads();
  }

  // epilogue: C/D layout col=lane&15, row=(lane>>4)*4+g  [verified m89/m91]
  const int rbase = m0 + wr * 64 + (lane >> 4) * 4;
  const int cbase = n0 + wc * 64 + (lane & 15);
#pragma unroll
  for (int i = 0; i < 4; i++) {
#pragma unroll
    for (int j = 0; j < 4; j++) {
      int col = cbase + j * 16;
      float badd = bias ? bias[col] : 0.f;
#pragma unroll
      for (int g = 0; g < 4; g++) {
        int row = rbase + i * 16 + g;
        Out[(size_t)row * N + col] = acc[i][j][g] + badd;
      }
    }
  }

  // fused scan stage-1 for the r projection: 32-row chunk column sums.
  // Each (chunk, col) is owned by exactly one wave of one block -> plain store.
  if (blockIdx.z == 1) {
    int b = m0 >> 11;
    int ch0 = ((m0 & (LL - 1)) >> 5) + wr * 2;
#pragma unroll
    for (int cp = 0; cp < 2; cp++) {
#pragma unroll
      for (int j = 0; j < 4; j++) {
        float s = 0.f;
#pragma unroll
        for (int i = cp * 2; i < cp * 2 + 2; i++)
#pragma unroll
          for (int g = 0; g < 4; g++) s += acc[i][j][g];
        s += __shfl_down(s, 32, 64);
        s += __shfl_down(s, 16, 64);
        if (lane < 16) {
          int col = n0 + wc * 64 + j * 16 + lane;
          chunks[((size_t)b * 64 + ch0 + cp) * EE + col] = s;
        }
      }
    }
  }
}

// ---------------- fused scan + score ----------------------------------------
// P[m] = prefix of r rows (in registers).  D[m] = (q_{L-1-m}+V) . P[m]
// S1[p] = (q_p+U).Kproj + (q_p+V).P[L]     (per-head dots over 64 lanes)
// grid (4 head-groups, 64 chunks, BB), block 256.
__global__ __launch_bounds__(256) void scan2f_kernel(
    const float* __restrict__ qbuf, const float* __restrict__ rbuf,
    const float* __restrict__ chunks, const float* __restrict__ Kproj,
    const float* __restrict__ U, const float* __restrict__ V,
    float* __restrict__ S1, float* __restrict__ Dbuf) {
  int tid = threadIdx.x, lane = tid & 63;
  int hg = blockIdx.x, ch = blockIdx.y, b = blockIdx.z;
  int e = hg * 256 + tid;
  int h = hg * 4 + (tid >> 6);
  float pre = 0.f, tot = 0.f;
  for (int c = 0; c < 64; c++) {           // 512 KB buffer, L2-resident
    float cs = chunks[((size_t)b * 64 + c) * EE + e];
    tot += cs;
    if (c < ch) pre += cs;
  }
  float kp = Kproj[b * EE + e], Ue = U[e], Ve = V[e];
  float run = pre;                          // == P[ch*32][e]
  size_t hoff = ((size_t)b * HH + h) * LL;
#pragma unroll 4
  for (int i = 0; i < 32; i++) {
    int m = ch * 32 + i;
    int p = LL - 1 - m;
    float qv = qbuf[((size_t)b * LL + p) * EE + e];
    float rv = rbuf[((size_t)b * LL + m) * EE + e];
    float tq = qv + Ve;
    float d = tq * run;                     // run == P[m]
    float s = tq * tot + (qv + Ue) * kp;
#pragma unroll
    for (int off = 32; off; off >>= 1) {
      d += __shfl_down(d, off, 64);
      s += __shfl_down(s, off, 64);
    }
    if (lane == 0) { Dbuf[hoff + m] = d; S1[hoff + p] = s; }
    run += rv;
  }
}

// ---------------- output: out[b,p,:] = sum_h S[b,h,p]*W2[b,h,:] + bo ---------
// S[b,h,p] = (S1[p] - D[L-1-p] + D[L-2-p]) / 32
__global__ __launch_bounds__(256) void out_kernel(
    const float* __restrict__ S1, const float* __restrict__ Dbuf,
    const float* __restrict__ W2, const float* __restrict__ bo,
    float* __restrict__ out) {
  int row = blockIdx.x;                   // [0, BB*LL)
  int b = row >> 11, p = row & (LL - 1);
  __shared__ float sh[HH];
  if (threadIdx.x < HH) {
    int h = threadIdx.x;
    size_t hoff = ((size_t)b * HH + h) * LL;
    float s1 = S1[hoff + p];
    float d1 = Dbuf[hoff + (LL - 1 - p)];
    float d2 = (p == LL - 1) ? 0.f : Dbuf[hoff + (LL - 2 - p)];
    sh[h] = (s1 - d1 + d2) * (1.f / 32.f);
  }
  __syncthreads();
  int e4 = threadIdx.x;                   // 256 float4 = 1024 floats
  const float4* W2v = (const float4*)W2;
  float4 acc = ((const float4*)bo)[e4];
#pragma unroll
  for (int h = 0; h < HH; h++) {
    float s = sh[h];
    float4 w = W2v[((size_t)b * HH + h) * 256 + e4];
    acc.x += s * w.x; acc.y += s * w.y; acc.z += s * w.z; acc.w += s * w.w;
  }
  ((float4*)out)[(size_t)row * 256 + e4] = acc;
}

extern "C" void kernel_launch(void* const* d_in, const int* in_sizes, int n_in,
                              void* d_out, int out_size, void* d_ws, size_t ws_size,
                              hipStream_t stream) {
  const float* query = (const float*)d_in[0];
  const float* key   = (const float*)d_in[1];
  const float* value = (const float*)d_in[2];
  const float* pos   = (const float*)d_in[3];
  const float* Wq = (const float*)d_in[4];
  const float* bq = (const float*)d_in[5];
  const float* Wk = (const float*)d_in[6];
  const float* bk = (const float*)d_in[7];
  const float* Wv = (const float*)d_in[8];
  const float* bv = (const float*)d_in[9];
  const float* Wp = (const float*)d_in[10];
  const float* Wo = (const float*)d_in[11];
  const float* bo = (const float*)d_in[12];
  const float* U  = (const float*)d_in[13];
  const float* V  = (const float*)d_in[14];
  float* out = (float*)d_out;

  char* ws = (char*)d_ws;
  size_t o = 0;
  auto take = [&](size_t bytes) -> char* {
    char* p = ws + o;
    o += (bytes + 255) & ~(size_t)255;
    return p;
  };
  float* keysum = (float*)take(BB * EE * 4);
  float* valsum = (float*)take(BB * EE * 4);
  float* Kproj  = (float*)take(BB * EE * 4);
  float* Vproj  = (float*)take(BB * EE * 4);
  float* W2     = (float*)take((size_t)BB * HH * EE * 4);
  float* S1     = (float*)take((size_t)BB * HH * LL * 4);
  float* Dbuf   = (float*)take((size_t)BB * HH * LL * 4);
  float* chunks = (float*)take((size_t)BB * 64 * EE * 4);
  float* qbuf   = (float*)take((size_t)BB * LL * EE * 4);
  float* rbuf   = (float*)take((size_t)BB * LL * EE * 4);
  unsigned short* q16  = (unsigned short*)take((size_t)BB * LL * EE * 2);
  unsigned short* pe16 = (unsigned short*)take((size_t)BB * LL * EE * 2);
  unsigned short* wq16 = (unsigned short*)take((size_t)EE * EE * 2);
  unsigned short* wp16 = (unsigned short*)take((size_t)EE * EE * 2);

  // zero the atomic accumulators (keysum, valsum are adjacent)
  hipMemsetAsync(keysum, 0, (size_t)2 * BB * EE * 4, stream);

  prelude_kernel<<<CAST_BLOCKS + 128, 256, 0, stream>>>(
      query, pos, Wq, Wp, q16, pe16, wq16, wp16, key, value, keysum, valsum);
  proj_kernel<<<dim3(BB * EE / 4, 1, 2), 256, 0, stream>>>(keysum, valsum, Wk, bk, Wv, bv, Kproj, Vproj);
  w2_kernel<<<dim3(BB * HH * EE / 4), 256, 0, stream>>>(Vproj, Wo, W2);
  gemm_kernel<<<dim3(EE / 128, BB * LL / 128, 2), 256, 0, stream>>>(
      q16, wq16, bq, qbuf, pe16, wp16, rbuf, chunks);
  scan2f_kernel<<<dim3(4, 64, BB), 256, 0, stream>>>(qbuf, rbuf, chunks, Kproj, U, V, S1, Dbuf);
  out_kernel<<<dim3(BB * LL), 256, 0, stream>>>(S1, Dbuf, W2, bo, out);
}